// Round 4
// baseline (980.066 us; speedup 1.0000x reference)
//
#include <hip/hip_runtime.h>
#include <hip/hip_bf16.h>
#include <math.h>

#define TBB 32
#define CC  256
#define NN  196
#define NJ  (TBB * NN)            // 6272
#define HD  1024
#define SLAB   ((size_t)TBB * CC * NN)   // 1,605,632
#define SLAB1K ((size_t)TBB * HD * NN)

typedef __attribute__((ext_vector_type(8))) short short8;
typedef __attribute__((ext_vector_type(4))) float floatx4;
typedef unsigned int  u32;
typedef unsigned short u16;
typedef unsigned char  u8;

struct Ptr6  { const float* p[6]; };
struct PtrM6 { float*       p[6]; };

__device__ inline u16 f2b(float f) {
    union { __hip_bfloat16 h; u16 u; } cv; cv.h = __float2bfloat16(f); return cv.u;
}
__device__ inline float b2f(u16 u) {
    union { __hip_bfloat16 h; u16 u; } cv; cv.u = u; return __bfloat162float(cv.h);
}

// ============================ R1 PROVEN KERNELS (verbatim) ==================
__global__ __launch_bounds__(256) void gemm_tile(
    const float* __restrict__ W,  const float* __restrict__ In,
    const float* __restrict__ W2, const float* __restrict__ In2,
    const float* __restrict__ bias, const float* __restrict__ bias2,
    float* __restrict__ Z, int Cout, int Cin)
{
    __shared__ float As[16][64];
    __shared__ float Bs[16][64];
    const int t  = threadIdx.x;
    const int tx = t & 15, ty = t >> 4;
    const int d0 = blockIdx.x * 64;
    const int j0 = blockIdx.y * 64;

    float acc[4][4] = {{0.f}};

    const int wrow = t >> 2;
    const int wk   = (t & 3) * 4;
    const int skk  = t >> 4;
    const int sj   = (t & 15) * 4;

    size_t inoff[4];
    {
        int jb = j0 + sj;
        #pragma unroll
        for (int i = 0; i < 4; ++i) {
            int j = jb + i;
            int m = j / NN;
            int n = j - m * NN;
            inoff[i] = (size_t)m * Cin * NN + n;
        }
    }

    for (int pass = 0; pass < 2; ++pass) {
        const float* Wp = pass ? W2 : W;
        const float* Ip = pass ? In2 : In;
        if (Wp == nullptr) break;
        for (int k0 = 0; k0 < Cin; k0 += 16) {
            float4 w4 = *(const float4*)(Wp + (size_t)(d0 + wrow) * Cin + (k0 + wk));
            float bvals[4];
            #pragma unroll
            for (int i = 0; i < 4; ++i)
                bvals[i] = Ip[inoff[i] + (size_t)(k0 + skk) * NN];

            As[wk + 0][wrow] = w4.x;
            As[wk + 1][wrow] = w4.y;
            As[wk + 2][wrow] = w4.z;
            As[wk + 3][wrow] = w4.w;
            #pragma unroll
            for (int i = 0; i < 4; ++i) Bs[skk][sj + i] = bvals[i];
            __syncthreads();

            #pragma unroll
            for (int kk = 0; kk < 16; ++kk) {
                float4 a4 = *(const float4*)(&As[kk][ty * 4]);
                float4 b4 = *(const float4*)(&Bs[kk][tx * 4]);
                float ar[4] = {a4.x, a4.y, a4.z, a4.w};
                float br[4] = {b4.x, b4.y, b4.z, b4.w};
                #pragma unroll
                for (int i = 0; i < 4; ++i)
                    #pragma unroll
                    for (int jj = 0; jj < 4; ++jj)
                        acc[i][jj] = fmaf(ar[i], br[jj], acc[i][jj]);
            }
            __syncthreads();
        }
    }

    #pragma unroll
    for (int i = 0; i < 4; ++i) {
        int d = d0 + ty * 4 + i;
        float bv = 0.f;
        if (bias)  bv += bias[d];
        if (bias2) bv += bias2[d];
        #pragma unroll
        for (int jj = 0; jj < 4; ++jj) {
            int j = j0 + tx * 4 + jj;
            int m = j / NN;
            int n = j - m * NN;
            Z[(size_t)(m * Cout + d) * NN + n] = acc[i][jj] + bv;
        }
    }
}

__global__ __launch_bounds__(256) void bn_stats(
    Ptr6 Zs, Ptr6 gs, Ptr6 bs, int Cout,
    float* __restrict__ scale, float* __restrict__ shift)
{
    const int d = blockIdx.x, g = blockIdx.y, t = threadIdx.x;
    const float* Z = Zs.p[g];
    double s = 0.0, s2 = 0.0;
    for (int i = t; i < NJ; i += 256) {
        int m = i / NN, n = i - m * NN;
        double v = (double)Z[(size_t)(m * Cout + d) * NN + n];
        s += v; s2 += v * v;
    }
    __shared__ double sh[256], sh2[256];
    sh[t] = s; sh2[t] = s2;
    __syncthreads();
    for (int off = 128; off > 0; off >>= 1) {
        if (t < off) { sh[t] += sh[t + off]; sh2[t] += sh2[t + off]; }
        __syncthreads();
    }
    if (t == 0) {
        double mu  = sh[0] / (double)NJ;
        double var = sh2[0] / (double)NJ - mu * mu;
        double a   = (double)gs.p[g][d] / sqrt(var + 1e-5);
        scale[g * Cout + d] = (float)a;
        shift[g * Cout + d] = (float)((double)bs.p[g][d] - mu * a);
    }
}

__global__ __launch_bounds__(256) void bn_apply(
    Ptr6 Zs, PtrM6 Ss, const float* __restrict__ scale,
    const float* __restrict__ shift, int Cout, int total)
{
    int g = blockIdx.y;
    int idx = blockIdx.x * 256 + threadIdx.x;
    if (idx >= total) return;
    int d = (idx / NN) % Cout;
    float v = fmaf(scale[g * Cout + d], Zs.p[g][idx], shift[g * Cout + d]);
    Ss.p[g][idx] = (v >= 1.f) ? 1.f : 0.f;
}

__global__ __launch_bounds__(256) void attention_f(
    const float* __restrict__ Q, const float* __restrict__ K,
    const float* __restrict__ V, const float* __restrict__ P,
    float* __restrict__ O)
{
    const int m = blockIdx.x;
    const int h = blockIdx.y;
    const int t = threadIdx.x;
    __shared__ unsigned int qb[196], kb[196], vb[196];
    __shared__ float Pl[841];

    if (P) { for (int i = t; i < 841; i += 256) Pl[i] = P[i]; }
    if (t < 196) {
        unsigned int q = 0, k = 0, v = 0;
        size_t base = (size_t)m * CC * NN + (size_t)h * 16 * NN + t;
        #pragma unroll
        for (int dd = 0; dd < 16; ++dd) {
            size_t off = base + (size_t)dd * NN;
            if (Q[off] > 0.5f) q |= (1u << dd);
            if (K[off] > 0.5f) k |= (1u << dd);
            if (V[off] > 0.5f) v |= (1u << dd);
        }
        qb[t] = q; kb[t] = k; vb[t] = v;
    }
    __syncthreads();

    if (t < 196) {
        int acc[16] = {0};
        const int ni = t / 14, nj = t - ni * 14;
        const unsigned int qr = qb[t];
        if (P) {
            for (int mm = 0; mm < 196; ++mm) {
                int a = __popc(qr & kb[mm]);
                int mi = mm / 14, mj = mm - mi * 14;
                float sv = (float)a + Pl[(ni - mi + 14) * 29 + (nj - mj + 14)];
                if (sv >= 1.f) {
                    unsigned int vv = vb[mm];
                    #pragma unroll
                    for (int dd = 0; dd < 16; ++dd)
                        acc[dd] += (vv >> dd) & 1;
                }
            }
        } else {
            for (int mm = 0; mm < 196; ++mm) {
                int a = __popc(qr & kb[mm]);
                if (a) {
                    unsigned int vv = vb[mm];
                    #pragma unroll
                    for (int dd = 0; dd < 16; ++dd)
                        acc[dd] += ((vv >> dd) & 1) ? a : 0;
                }
            }
        }
        size_t base = (size_t)m * CC * NN + (size_t)h * 16 * NN + t;
        #pragma unroll
        for (int dd = 0; dd < 16; ++dd)
            O[base + (size_t)dd * NN] = (acc[dd] >= 2) ? 1.f : 0.f;
    }
}

__global__ __launch_bounds__(256) void add_residual2(
    const float* __restrict__ x, const float* __restrict__ y,
    const float* __restrict__ sx, const float* __restrict__ sy,
    float* __restrict__ X1, float* __restrict__ Y1)
{
    size_t i = (size_t)blockIdx.x * 256 + threadIdx.x;
    if (i >= SLAB) return;
    X1[i] = x[i] + sx[i];
    Y1[i] = y[i] + sy[i];
}

__global__ __launch_bounds__(256) void lif1(
    const float* __restrict__ Z, float* __restrict__ S, int total)
{
    int i = blockIdx.x * 256 + threadIdx.x;
    if (i >= total) return;
    S[i] = (Z[i] >= 1.f) ? 1.f : 0.f;
}

// out = cur + o, plus diagnostic poison: out[0] += 1000 * flagmask
__global__ __launch_bounds__(256) void final_add_flag(
    const float* __restrict__ cur, const float* __restrict__ o,
    float* __restrict__ out, int total, const u32* __restrict__ flags)
{
    int i = blockIdx.x * 256 + threadIdx.x;
    if (i >= total) return;
    float v = cur[i] + o[i];
    if (i == 0) v += 1000.0f * (float)flags[0];
    out[i] = v;
}

// ============================ NEW-PATH KERNELS (under test) =================
struct SplitP {
    const float* src[4]; u16* dst[4];
    int total[4]; int cols[4]; int term[4];
};
__global__ __launch_bounds__(256) void split_w(SplitP p)
{
    int sg = blockIdx.y;
    int idx = blockIdx.x * 256 + threadIdx.x;
    if (idx >= p.total[sg]) return;
    float w = p.src[sg][idx];
    u16 h0 = f2b(w);      float r1 = w  - b2f(h0);
    u16 h1 = f2b(r1);     float r2 = r1 - b2f(h1);
    u16 h2 = f2b(r2);
    u16* d = p.dst[sg] + idx;
    size_t ts = p.term[sg];
    d[0] = h0; d[ts] = h1; d[2*ts] = h2;
}

// BN apply + bit-pack (same fmaf as bn_apply -> bitwise identical decision)
__global__ __launch_bounds__(256) void bn_apply_pack(
    const float* __restrict__ Z, u32* __restrict__ dst,
    const float* __restrict__ sc, const float* __restrict__ sh,
    int Cout, int wpc, int woff)
{
    int m = blockIdx.x, w = blockIdx.y;
    int n = threadIdx.x;
    if (n >= NN) return;
    u32 bits = 0;
    #pragma unroll 8
    for (int dd = 0; dd < 32; ++dd) {
        int c = w * 32 + dd;
        float v = fmaf(sc[c], Z[((size_t)m * Cout + c) * NN + n], sh[c]);
        bits |= (v >= 1.f ? 1u : 0u) << dd;
    }
    dst[(size_t)(m * NN + n) * wpc + woff + w] = bits;
}

// pack float spikes (0/1) into bits
__global__ __launch_bounds__(256) void pack_spikes(
    const float* __restrict__ S, u32* __restrict__ dst, int Cout, int wpc)
{
    int m = blockIdx.x, w = blockIdx.y;
    int n = threadIdx.x;
    if (n >= NN) return;
    u32 bits = 0;
    #pragma unroll 8
    for (int dd = 0; dd < 32; ++dd) {
        int c = w * 32 + dd;
        bits |= (S[((size_t)m * Cout + c) * NN + n] > 0.5f ? 1u : 0u) << dd;
    }
    dst[(size_t)(m * NN + n) * wpc + w] = bits;
}

// compare packed words against float spike slab -> flag bit on mismatch
__global__ __launch_bounds__(256) void check_pack(
    const float* __restrict__ S, const u32* __restrict__ packed,
    int Cout, int wpc, int woff, u32 bit, u32* __restrict__ flags)
{
    int m = blockIdx.x, w = blockIdx.y;
    int n = threadIdx.x;
    if (n >= NN) return;
    u32 bits = 0;
    #pragma unroll 8
    for (int dd = 0; dd < 32; ++dd) {
        int c = w * 32 + dd;
        bits |= (S[((size_t)m * Cout + c) * NN + n] > 0.5f ? 1u : 0u) << dd;
    }
    if (bits != packed[(size_t)(m * NN + n) * wpc + woff + w]) atomicOr(flags, bit);
}

// packed attention (under test) — same math as attention_f but packed I/O
__global__ __launch_bounds__(256) void attn_packed(
    const u16* __restrict__ qp, const u16* __restrict__ kp,
    const u16* __restrict__ vp, const float* __restrict__ P,
    u16* __restrict__ op)
{
    const int m = blockIdx.x, h = blockIdx.y, t = threadIdx.x;
    __shared__ u32 kb[196], vb[196];
    __shared__ float Pl[841];
    if (P) { for (int i = t; i < 841; i += 256) Pl[i] = P[i]; }
    if (t < 196) {
        kb[t] = kp[(m*196 + t)*16 + h];
        vb[t] = vp[(m*196 + t)*16 + h];
    }
    __syncthreads();
    if (t < 196) {
        u32 qr = qp[(m*196 + t)*16 + h];
        int acc[16] = {0};
        const int ni = t / 14, nj = t - ni * 14;
        if (P) {
            for (int mm = 0; mm < 196; ++mm) {
                int a = __popc(qr & kb[mm]);
                int mi = mm / 14, mj = mm - mi * 14;
                float sv = (float)a + Pl[(ni - mi + 14)*29 + (nj - mj + 14)];
                if (sv >= 1.f) {
                    u32 vv = vb[mm];
                    #pragma unroll
                    for (int dd = 0; dd < 16; ++dd) acc[dd] += (vv >> dd) & 1;
                }
            }
        } else {
            for (int mm = 0; mm < 196; ++mm) {
                int a = __popc(qr & kb[mm]);
                if (a) {
                    u32 vv = vb[mm];
                    #pragma unroll
                    for (int dd = 0; dd < 16; ++dd) acc[dd] += ((vv >> dd) & 1) ? a : 0;
                }
            }
        }
        u16 bits = 0;
        #pragma unroll
        for (int dd = 0; dd < 16; ++dd) bits |= (acc[dd] >= 2 ? 1u : 0u) << dd;
        op[(m*196 + t)*16 + h] = bits;
    }
}

// bgemm core (under test): compute with split-bf16 MFMA, COMPARE vs truth.
__global__ __launch_bounds__(256) void bgemm_check(
    const u16* __restrict__ Wsp, const u8* __restrict__ Bp,
    int M, int K, const float* __restrict__ truth,
    const float* __restrict__ bias, u32 bit, u32* __restrict__ flags)
{
    const int t  = threadIdx.x;
    const int wv = t >> 6, ln = t & 63;
    const int lo = ln & 15, qd = ln >> 4;
    const int d0 = blockIdx.x * 128;
    const int j0 = blockIdx.y * 64;

    __shared__ short8 lut[256];
    {
        short8 e;
        #pragma unroll
        for (int i = 0; i < 8; ++i) e[i] = (short)(((t >> i) & 1) ? 0x3F80 : 0);
        lut[t] = e;
    }
    __syncthreads();

    floatx4 acc[2][4];
    #pragma unroll
    for (int a = 0; a < 2; ++a)
        #pragma unroll
        for (int b = 0; b < 4; ++b)
            #pragma unroll
            for (int r = 0; r < 4; ++r) acc[a][b][r] = 0.f;

    const int colB = K >> 3;
    const u8* bcol[4];
    #pragma unroll
    for (int nt = 0; nt < 4; ++nt)
        bcol[nt] = Bp + (size_t)(j0 + nt*16 + lo) * colB + qd;
    const u16* arow[2][3];
    #pragma unroll
    for (int mt = 0; mt < 2; ++mt)
        #pragma unroll
        for (int tm = 0; tm < 3; ++tm)
            arow[mt][tm] = Wsp + ((size_t)tm * M + (d0 + wv*32 + mt*16 + lo)) * K + qd*8;

    for (int k0 = 0; k0 < K; k0 += 32) {
        short8 bf[4];
        #pragma unroll
        for (int nt = 0; nt < 4; ++nt) bf[nt] = lut[bcol[nt][k0 >> 3]];
        #pragma unroll
        for (int mt = 0; mt < 2; ++mt) {
            #pragma unroll
            for (int tm = 0; tm < 3; ++tm) {
                short8 af = *(const short8*)(arow[mt][tm] + k0);
                #pragma unroll
                for (int nt = 0; nt < 4; ++nt)
                    acc[mt][nt] = __builtin_amdgcn_mfma_f32_16x16x32_bf16(af, bf[nt], acc[mt][nt], 0, 0, 0);
            }
        }
    }

    #pragma unroll
    for (int mt = 0; mt < 2; ++mt)
        #pragma unroll
        for (int nt = 0; nt < 4; ++nt) {
            int j = j0 + nt*16 + lo;
            int m = j / NN, n = j - m * NN;
            #pragma unroll
            for (int r = 0; r < 4; ++r) {
                int d = d0 + wv*32 + mt*16 + qd*4 + r;
                float v = acc[mt][nt][r] + (bias ? bias[d] : 0.f);
                float tr = truth[((size_t)m * M + d) * NN + n];
                if (fabsf(v - tr) > 3e-3f) atomicOr(flags, bit);
            }
        }
}

// ---------------------------------------------------------------------------
extern "C" void kernel_launch(void* const* d_in, const int* in_sizes, int n_in,
                              void* d_out, int out_size, void* d_ws, size_t ws_size,
                              hipStream_t stream)
{
    const float* x     = (const float*)d_in[0];
    const float* y     = (const float*)d_in[1];
    const float* av_w  = (const float*)d_in[2];
    const float* av_g  = (const float*)d_in[3];
    const float* av_b  = (const float*)d_in[4];
    const float* va_w  = (const float*)d_in[5];
    const float* va_g  = (const float*)d_in[6];
    const float* va_b  = (const float*)d_in[7];
    const float* P_rpb = (const float*)d_in[8];
    const float* fc1_w = (const float*)d_in[9];
    const float* fc1_b = (const float*)d_in[10];
    const float* fc2_w = (const float*)d_in[11];
    const float* fc2_b = (const float*)d_in[12];
    const float* m1_w  = (const float*)d_in[13];
    const float* m1_b  = (const float*)d_in[14];
    const float* m1_g  = (const float*)d_in[15];
    const float* m1_bb = (const float*)d_in[16];
    const float* m2_w  = (const float*)d_in[17];
    const float* m2_b  = (const float*)d_in[18];
    const float* m2_g  = (const float*)d_in[19];
    const float* m2_bb = (const float*)d_in[20];
    float* out = (float*)d_out;
    const size_t CC2 = (size_t)CC * CC;

    // ---- workspace: R1 layout first, debug region appended --------------
    char* wsb = (char*)d_ws;
    size_t off = 0;
    auto alloc = [&](size_t bytes) { void* p = wsb + off; off += (bytes + 255) & ~(size_t)255; return p; };
    u32*   flags = (u32*)alloc(256);
    float* A     = (float*)alloc(6 * SLAB * 4);
    float* Bf    = (float*)alloc(2 * SLAB * 4);
    float* Cf    = (float*)alloc(2 * SLAB * 4);
    float* scale = (float*)alloc(6 * 1024 * 4);
    float* shift = (float*)alloc(6 * 1024 * 4);
    size_t r1_end = off;
    // debug region
    u32* qkvp[6];
    for (int i = 0; i < 6; ++i) qkvp[i] = (u32*)alloc((size_t)NJ * 8 * 4);
    u32* opAp = (u32*)alloc((size_t)NJ * 8 * 4);
    u32* opVp = (u32*)alloc((size_t)NJ * 8 * 4);
    u32* curp = (u32*)alloc((size_t)NJ * 8 * 4);
    u32* hpack= (u32*)alloc((size_t)NJ * 32 * 4);
    u16* W3sA = (u16*)alloc(3 * CC2 * 2);
    u16* W3sV = (u16*)alloc(3 * CC2 * 2);
    u16* m1s  = (u16*)alloc((size_t)3 * HD * CC * 2);
    u16* m2s  = (u16*)alloc((size_t)3 * CC * HD * 2);
    const bool dbg = (ws_size >= off);
    (void)r1_end;

    hipMemsetAsync(flags, 0, 4, stream);

    const int blocksSlab  = (int)(SLAB / 256);
    const int blocksSlab1 = (int)(SLAB1K / 256);

    if (dbg) {
        SplitP sp{};
        sp.src[0] = av_w + 3*CC2; sp.dst[0] = W3sA; sp.total[0] = 65536;  sp.cols[0] = 256;  sp.term[0] = 65536;
        sp.src[1] = va_w + 3*CC2; sp.dst[1] = W3sV; sp.total[1] = 65536;  sp.cols[1] = 256;  sp.term[1] = 65536;
        sp.src[2] = m1_w;         sp.dst[2] = m1s;  sp.total[2] = 262144; sp.cols[2] = 256;  sp.term[2] = 262144;
        sp.src[3] = m2_w;         sp.dst[3] = m2s;  sp.total[3] = 262144; sp.cols[3] = 1024; sp.term[3] = 262144;
        split_w<<<dim3(1024, 4), 256, 0, stream>>>(sp);
    }

    // ---- Stage A: 6 first-layer convs (R1 verbatim) ---------------------
    const float* Wl[6] = { av_w, av_w + CC2, av_w + 2*CC2, va_w, va_w + CC2, va_w + 2*CC2 };
    const float* Il[6] = { x, y, y, y, x, x };
    for (int i = 0; i < 6; ++i)
        gemm_tile<<<dim3(CC/64, NJ/64), 256, 0, stream>>>(
            Wl[i], Il[i], nullptr, nullptr, nullptr, nullptr, A + i*SLAB, CC, CC);

    Ptr6 Zs{}, gs{}, bs{}; PtrM6 Ss{};
    const float* gl[6] = { av_g, av_g + CC, av_g + 2*CC, va_g, va_g + CC, va_g + 2*CC };
    const float* bl[6] = { av_b, av_b + CC, av_b + 2*CC, va_b, va_b + CC, va_b + 2*CC };
    for (int i = 0; i < 6; ++i) {
        Zs.p[i] = A + i*SLAB; Ss.p[i] = A + i*SLAB; gs.p[i] = gl[i]; bs.p[i] = bl[i];
    }
    bn_stats<<<dim3(CC, 6), 256, 0, stream>>>(Zs, gs, bs, CC, scale, shift);
    if (dbg)
        for (int i = 0; i < 6; ++i)
            bn_apply_pack<<<dim3(32, 8), 256, 0, stream>>>(
                A + i*SLAB, qkvp[i], scale + i*CC, shift + i*CC, CC, 8, 0);
    bn_apply<<<dim3(blocksSlab, 6), 256, 0, stream>>>(Zs, Ss, scale, shift, CC, (int)SLAB);
    if (dbg)
        for (int i = 0; i < 6; ++i)
            check_pack<<<dim3(32, 8), 256, 0, stream>>>(
                A + i*SLAB, qkvp[i], CC, 8, 0, 1u << 0, flags);

    // ---- Stage B: attention (R1 float path) -----------------------------
    attention_f<<<dim3(TBB, 16), 256, 0, stream>>>(A, A + SLAB, A + 2*SLAB, nullptr, Bf);
    attention_f<<<dim3(TBB, 16), 256, 0, stream>>>(A + 3*SLAB, A + 4*SLAB, A + 5*SLAB, P_rpb, Bf + SLAB);
    if (dbg) {
        attn_packed<<<dim3(TBB, 16), 256, 0, stream>>>((u16*)qkvp[0], (u16*)qkvp[1], (u16*)qkvp[2], nullptr, (u16*)opAp);
        attn_packed<<<dim3(TBB, 16), 256, 0, stream>>>((u16*)qkvp[3], (u16*)qkvp[4], (u16*)qkvp[5], P_rpb,   (u16*)opVp);
        check_pack<<<dim3(32, 8), 256, 0, stream>>>(Bf,        opAp, CC, 8, 0, 1u << 1, flags);
        check_pack<<<dim3(32, 8), 256, 0, stream>>>(Bf + SLAB, opVp, CC, 8, 0, 1u << 1, flags);
    }

    // ---- Stage C: W3 conv (R1) + bgemm core check -----------------------
    gemm_tile<<<dim3(CC/64, NJ/64), 256, 0, stream>>>(
        av_w + 3*CC2, Bf, nullptr, nullptr, nullptr, nullptr, Cf, CC, CC);
    gemm_tile<<<dim3(CC/64, NJ/64), 256, 0, stream>>>(
        va_w + 3*CC2, Bf + SLAB, nullptr, nullptr, nullptr, nullptr, Cf + SLAB, CC, CC);
    if (dbg) {
        bgemm_check<<<dim3(2, 98), 256, 0, stream>>>(W3sA, (const u8*)opAp, 256, 256, Cf,        nullptr, 1u << 2, flags);
        bgemm_check<<<dim3(2, 98), 256, 0, stream>>>(W3sV, (const u8*)opVp, 256, 256, Cf + SLAB, nullptr, 1u << 2, flags);
    }
    Zs.p[0] = Cf; Zs.p[1] = Cf + SLAB; Ss.p[0] = Cf; Ss.p[1] = Cf + SLAB;
    gs.p[0] = av_g + 3*CC; gs.p[1] = va_g + 3*CC;
    bs.p[0] = av_b + 3*CC; bs.p[1] = va_b + 3*CC;
    bn_stats<<<dim3(CC, 2), 256, 0, stream>>>(Zs, gs, bs, CC, scale, shift);
    bn_apply<<<dim3(blocksSlab, 2), 256, 0, stream>>>(Zs, Ss, scale, shift, CC, (int)SLAB);

    // ---- residual + fc + cur (R1) ---------------------------------------
    add_residual2<<<blocksSlab, 256, 0, stream>>>(x, y, Cf, Cf + SLAB, A, A + SLAB);
    gemm_tile<<<dim3(CC/64, NJ/64), 256, 0, stream>>>(
        fc1_w, A, fc2_w, A + SLAB, fc1_b, fc2_b, Bf, CC, CC);
    lif1<<<blocksSlab, 256, 0, stream>>>(Bf, Bf + SLAB, (int)SLAB);
    if (dbg)
        pack_spikes<<<dim3(32, 8), 256, 0, stream>>>(Bf + SLAB, curp, CC, 8);

    // ---- m1 (R1) + bgemm M=1024 check -----------------------------------
    gemm_tile<<<dim3(HD/64, NJ/64), 256, 0, stream>>>(
        m1_w, Bf + SLAB, nullptr, nullptr, m1_b, nullptr, A, HD, CC);
    if (dbg)
        bgemm_check<<<dim3(8, 98), 256, 0, stream>>>(m1s, (const u8*)curp, 1024, 256, A, m1_b, 1u << 3, flags);
    Zs.p[0] = A; Ss.p[0] = A; gs.p[0] = m1_g; bs.p[0] = m1_bb;
    bn_stats<<<dim3(HD, 1), 256, 0, stream>>>(Zs, gs, bs, HD, scale, shift);
    bn_apply<<<dim3(blocksSlab1, 1), 256, 0, stream>>>(Zs, Ss, scale, shift, HD, (int)SLAB1K);
    if (dbg)
        pack_spikes<<<dim3(32, 32), 256, 0, stream>>>(A, hpack, HD, 32);

    // ---- m2 (R1) + bgemm K=1024 check -----------------------------------
    gemm_tile<<<dim3(CC/64, NJ/64), 256, 0, stream>>>(
        m2_w, A, nullptr, nullptr, m2_b, nullptr, Cf, CC, HD);
    if (dbg)
        bgemm_check<<<dim3(2, 98), 256, 0, stream>>>(m2s, (const u8*)hpack, 256, 1024, Cf, m2_b, 1u << 4, flags);
    Zs.p[0] = Cf; Ss.p[0] = Cf; gs.p[0] = m2_g; bs.p[0] = m2_bb;
    bn_stats<<<dim3(CC, 1), 256, 0, stream>>>(Zs, gs, bs, CC, scale, shift);
    bn_apply<<<dim3(blocksSlab, 1), 256, 0, stream>>>(Zs, Ss, scale, shift, CC, (int)SLAB);

    // ---- out = cur + o (+ diagnostic poison at [0]) ---------------------
    final_add_flag<<<blocksSlab, 256, 0, stream>>>(Bf + SLAB, Cf, out, (int)SLAB, flags);
}